// Round 3
// baseline (315.605 us; speedup 1.0000x reference)
//
#include <hip/hip_runtime.h>

typedef __bf16 bf16x8 __attribute__((ext_vector_type(8)));
typedef float f32x4 __attribute__((ext_vector_type(4)));
typedef unsigned int u32x4 __attribute__((ext_vector_type(4)));
typedef unsigned short u16;
typedef unsigned int u32;

// ---- constants for this problem ----
#define BSZ 2
#define TSEQ 2048
#define DMODEL 1024
#define NHEAD 16
#define DHEAD 64

__device__ __forceinline__ u16 f2bf(float f) {
  u32 u = __builtin_bit_cast(u32, f);
  u32 r = (u + 0x7fffu + ((u >> 16) & 1u)) >> 16;   // RNE
  return (u16)r;
}
__device__ __forceinline__ float bf2f(u16 h) {
  return __builtin_bit_cast(float, (u32)h << 16);
}

// ---------------- fp32 -> bf16 convert (4 elems/thread) ----------------
__global__ void k_cvt(const float* __restrict__ in, u16* __restrict__ out, int n4) {
  int i = blockIdx.x * 256 + threadIdx.x;
  if (i >= n4) return;
  float4 v = ((const float4*)in)[i];
  ushort4 o;
  o.x = f2bf(v.x); o.y = f2bf(v.y); o.z = f2bf(v.z); o.w = f2bf(v.w);
  ((ushort4*)out)[i] = o;
}

// ------------- transpose + convert: in [K][N] f32 -> out [N][K] bf16 -------------
__global__ void k_transpose_cvt(const float* __restrict__ in, u16* __restrict__ out,
                                int K, int N) {
  __shared__ float tile[64][65];
  int n0 = blockIdx.x * 64, k0 = blockIdx.y * 64;
  int tx = threadIdx.x & 63, ty = threadIdx.x >> 6;
#pragma unroll
  for (int i = ty; i < 64; i += 4)
    tile[i][tx] = in[(size_t)(k0 + i) * N + n0 + tx];
  __syncthreads();
#pragma unroll
  for (int i = ty; i < 64; i += 4)
    out[(size_t)(n0 + i) * K + k0 + tx] = f2bf(tile[tx][i]);
}

// ---------------- RoPE cos/sin table: [T][32] each ----------------
__global__ void k_rope_table(float* __restrict__ cosT, float* __restrict__ sinT) {
  int idx = blockIdx.x * 256 + threadIdx.x;  // T*32
  int t = idx >> 5, f = idx & 31;
  float inv_freq = powf(10000.0f, -(float)(2 * f) / 64.0f);
  float ang = (float)t * inv_freq;
  float s, c;
  sincosf(ang, &s, &c);
  cosT[idx] = c;
  sinT[idx] = s;
}

// ---------------- GEMM: C[M][N] = A[M][K] * Bt[N][K]^T  (bf16 in, template out) ----------------
__device__ __forceinline__ void store_out(u16* C, size_t i, float v) { C[i] = f2bf(v); }
__device__ __forceinline__ void store_out(float* C, size_t i, float v) { C[i] = v; }

template <typename OutT>
__global__ __launch_bounds__(256) void k_gemm(const u16* __restrict__ A,
                                              const u16* __restrict__ Bt,
                                              OutT* __restrict__ C, int M, int N, int K) {
  __shared__ __align__(16) u16 a_lds[128][40];
  __shared__ __align__(16) u16 b_lds[128][40];
  int m0 = blockIdx.y * 128, n0 = blockIdx.x * 128;
  int tid = threadIdx.x;
  int w = tid >> 6, l = tid & 63, lr = l & 15, lg = l >> 4;
  int wr = (w >> 1) * 64, wc = (w & 1) * 64;
  int sr = tid >> 2;        // 0..63 staging row
  int sc = (tid & 3) * 8;   // k-chunk (8 bf16 = 16B)
  f32x4 acc[4][4] = {};

  const u16* ap0 = A + (size_t)(m0 + sr) * K + sc;
  const u16* ap1 = A + (size_t)(m0 + sr + 64) * K + sc;
  const u16* bp0 = Bt + (size_t)(n0 + sr) * K + sc;
  const u16* bp1 = Bt + (size_t)(n0 + sr + 64) * K + sc;

  u32x4 ra0 = *(const u32x4*)ap0;
  u32x4 ra1 = *(const u32x4*)ap1;
  u32x4 rb0 = *(const u32x4*)bp0;
  u32x4 rb1 = *(const u32x4*)bp1;

  for (int k0 = 0; k0 < K; k0 += 32) {
    *(u32x4*)&a_lds[sr][sc] = ra0;
    *(u32x4*)&a_lds[sr + 64][sc] = ra1;
    *(u32x4*)&b_lds[sr][sc] = rb0;
    *(u32x4*)&b_lds[sr + 64][sc] = rb1;
    __syncthreads();
    if (k0 + 32 < K) {   // prefetch next tile while computing this one
      ra0 = *(const u32x4*)(ap0 + k0 + 32);
      ra1 = *(const u32x4*)(ap1 + k0 + 32);
      rb0 = *(const u32x4*)(bp0 + k0 + 32);
      rb1 = *(const u32x4*)(bp1 + k0 + 32);
    }
    bf16x8 af[4], bfv[4];
#pragma unroll
    for (int mt = 0; mt < 4; ++mt)
      af[mt] = __builtin_bit_cast(bf16x8, *(const u32x4*)&a_lds[wr + mt * 16 + lr][lg * 8]);
#pragma unroll
    for (int nt = 0; nt < 4; ++nt)
      bfv[nt] = __builtin_bit_cast(bf16x8, *(const u32x4*)&b_lds[wc + nt * 16 + lr][lg * 8]);
#pragma unroll
    for (int mt = 0; mt < 4; ++mt)
#pragma unroll
      for (int nt = 0; nt < 4; ++nt)
        acc[mt][nt] = __builtin_amdgcn_mfma_f32_16x16x32_bf16(af[mt], bfv[nt], acc[mt][nt], 0, 0, 0);
    __syncthreads();
  }

#pragma unroll
  for (int mt = 0; mt < 4; ++mt)
#pragma unroll
    for (int nt = 0; nt < 4; ++nt)
#pragma unroll
      for (int r = 0; r < 4; ++r) {
        int row = m0 + wr + mt * 16 + lg * 4 + r;
        int col = n0 + wc + nt * 16 + lr;
        store_out(C, (size_t)row * N + col, acc[mt][nt][r]);
      }
}

// ---------------- RoPE apply + [B,T,3D] -> [B,H,T,DH] split ----------------
// idx = ((b*16+h)*2048 + t)*64 + d ; Q pre-scaled by DH^-0.5
__global__ void k_rope_apply(const u16* __restrict__ qkv, const float* __restrict__ cosT,
                             const float* __restrict__ sinT, u16* __restrict__ Q,
                             u16* __restrict__ K, u16* __restrict__ V) {
  int idx = blockIdx.x * 256 + threadIdx.x;
  int d = idx & 63;
  int t = (idx >> 6) & 2047;
  int h = (idx >> 17) & 15;
  int b = idx >> 21;
  size_t row = (size_t)(b * TSEQ + t) * (3 * DMODEL);
  int cq = h * 64 + d;
  int cp = h * 64 + (d ^ 32);
  float q  = bf2f(qkv[row + cq]);
  float qp = bf2f(qkv[row + cp]);
  float k  = bf2f(qkv[row + DMODEL + cq]);
  float kp = bf2f(qkv[row + DMODEL + cp]);
  float v  = bf2f(qkv[row + 2 * DMODEL + cq]);
  int f = d & 31;
  float c = cosT[t * 32 + f], s = sinT[t * 32 + f];
  float sgn = (d < 32) ? -1.0f : 1.0f;
  float qr = (q * c + sgn * qp * s) * 0.125f;  // fold score scale into Q (exact pow2)
  float kr = k * c + sgn * kp * s;
  Q[idx] = f2bf(qr);
  K[idx] = f2bf(kr);
  V[idx] = f2bf(v);
}

// ---------------- flash attention (causal), QBLK=64, KVBLK=64, 4 waves ----------------
__global__ __launch_bounds__(256) void k_flash(const u16* __restrict__ Qg, const u16* __restrict__ Kg,
                                               const u16* __restrict__ Vg, u16* __restrict__ O) {
  __shared__ __align__(16) u16 k_lds[64][72];
  __shared__ __align__(16) u16 vt_lds[64][72];
  __shared__ __align__(16) u16 p_lds[4][16][72];
  int qb = gridDim.x - 1 - blockIdx.x;  // heavy blocks first
  int bh = blockIdx.y;                  // b*16+h
  int b = bh >> 4, h = bh & 15;
  size_t hoff = (size_t)bh * TSEQ * DHEAD;
  int tid = threadIdx.x, w = tid >> 6, l = tid & 63, lr = l & 15, lg = l >> 4;

  // Q fragments (held in registers for the whole block)
  int qrow = qb * 64 + w * 16 + lr;
  const u16* qp = Qg + hoff + (size_t)qrow * 64 + lg * 8;
  bf16x8 qf0 = __builtin_bit_cast(bf16x8, *(const u32x4*)qp);
  bf16x8 qf1 = __builtin_bit_cast(bf16x8, *(const u32x4*)(qp + 32));

  f32x4 acc[4] = {};
  float mrow[4] = {-1e30f, -1e30f, -1e30f, -1e30f};
  float lrow[4] = {0.f, 0.f, 0.f, 0.f};

  int srow = tid >> 3;        // 0..31
  int sc8 = (tid & 7) * 8;

  for (int kv = 0; kv <= qb; ++kv) {
    __syncthreads();
    const u16* kb = Kg + hoff + (size_t)(kv * 64) * 64;
    const u16* vb = Vg + hoff + (size_t)(kv * 64) * 64;
#pragma unroll
    for (int p = 0; p < 2; ++p) {
      int r = srow + p * 32;
      *(u32x4*)&k_lds[r][sc8] = *(const u32x4*)(kb + (size_t)r * 64 + sc8);
      u32x4 vv = *(const u32x4*)(vb + (size_t)r * 64 + sc8);
      u16* pv = (u16*)&vv;
#pragma unroll
      for (int e = 0; e < 8; ++e) vt_lds[sc8 + e][r] = pv[e];  // transpose into Vt
    }
    __syncthreads();

    // S = (Q*scale) K^T  -- 16x64 per wave
    f32x4 s[4];
#pragma unroll
    for (int c = 0; c < 4; ++c) {
      const u16* kp2 = &k_lds[c * 16 + lr][lg * 8];
      bf16x8 kf0 = __builtin_bit_cast(bf16x8, *(const u32x4*)kp2);
      bf16x8 kf1 = __builtin_bit_cast(bf16x8, *(const u32x4*)(kp2 + 32));
      f32x4 z = {};
      z = __builtin_amdgcn_mfma_f32_16x16x32_bf16(qf0, kf0, z, 0, 0, 0);
      s[c] = __builtin_amdgcn_mfma_f32_16x16x32_bf16(qf1, kf1, z, 0, 0, 0);
    }
    if (kv == qb) {  // diagonal block: causal mask (col > row)
#pragma unroll
      for (int c = 0; c < 4; ++c)
#pragma unroll
        for (int r = 0; r < 4; ++r)
          if (c * 16 + lr > w * 16 + lg * 4 + r) s[c][r] = -1e30f;
    }

    // online softmax: rows live across 16-lane groups (cols), 4 rows/lane
    float rmax[4], rsum[4], alpha[4];
#pragma unroll
    for (int r = 0; r < 4; ++r)
      rmax[r] = fmaxf(fmaxf(s[0][r], s[1][r]), fmaxf(s[2][r], s[3][r]));
#pragma unroll
    for (int mset = 1; mset <= 8; mset <<= 1)
#pragma unroll
      for (int r = 0; r < 4; ++r)
        rmax[r] = fmaxf(rmax[r], __shfl_xor(rmax[r], mset, 64));
#pragma unroll
    for (int r = 0; r < 4; ++r) {
      float mn = fmaxf(mrow[r], rmax[r]);
      alpha[r] = __expf(mrow[r] - mn);
      mrow[r] = mn;
      rsum[r] = 0.0f;
    }
#pragma unroll
    for (int c = 0; c < 4; ++c)
#pragma unroll
      for (int r = 0; r < 4; ++r) {
        float pe = __expf(s[c][r] - mrow[r]);
        s[c][r] = pe;
        rsum[r] += pe;
      }
#pragma unroll
    for (int mset = 1; mset <= 8; mset <<= 1)
#pragma unroll
      for (int r = 0; r < 4; ++r)
        rsum[r] += __shfl_xor(rsum[r], mset, 64);
#pragma unroll
    for (int r = 0; r < 4; ++r)
      lrow[r] = lrow[r] * alpha[r] + rsum[r];
#pragma unroll
    for (int n = 0; n < 4; ++n)
#pragma unroll
      for (int r = 0; r < 4; ++r)
        acc[n][r] *= alpha[r];

    // P (fp32, D-layout) -> bf16 LDS -> A-fragments. Wave-local: no barrier needed.
#pragma unroll
    for (int c = 0; c < 4; ++c)
#pragma unroll
      for (int r = 0; r < 4; ++r)
        p_lds[w][lg * 4 + r][c * 16 + lr] = f2bf(s[c][r]);
    bf16x8 pa0 = __builtin_bit_cast(bf16x8, *(const u32x4*)&p_lds[w][lr][lg * 8]);
    bf16x8 pa1 = __builtin_bit_cast(bf16x8, *(const u32x4*)&p_lds[w][lr][lg * 8 + 32]);

#pragma unroll
    for (int n = 0; n < 4; ++n) {
      const u16* vp = &vt_lds[n * 16 + lr][lg * 8];
      bf16x8 v0 = __builtin_bit_cast(bf16x8, *(const u32x4*)vp);
      bf16x8 v1 = __builtin_bit_cast(bf16x8, *(const u32x4*)(vp + 32));
      acc[n] = __builtin_amdgcn_mfma_f32_16x16x32_bf16(pa0, v0, acc[n], 0, 0, 0);
      acc[n] = __builtin_amdgcn_mfma_f32_16x16x32_bf16(pa1, v1, acc[n], 0, 0, 0);
    }
  }

  // epilogue: normalize, write [B,T,H*DH]
#pragma unroll
  for (int n = 0; n < 4; ++n)
#pragma unroll
    for (int r = 0; r < 4; ++r) {
      int t = qb * 64 + w * 16 + lg * 4 + r;
      int dd = n * 16 + lr;
      float ov = acc[n][r] / lrow[r];
      O[(size_t)(b * TSEQ + t) * DMODEL + h * 64 + dd] = f2bf(ov);
    }
}

extern "C" void kernel_launch(void* const* d_in, const int* in_sizes, int n_in,
                              void* d_out, int out_size, void* d_ws, size_t ws_size,
                              hipStream_t stream) {
  const float* x     = (const float*)d_in[0];  // [2,2048,1024]
  const float* w_qkv = (const float*)d_in[1];  // [1024,3072]
  const float* w_out = (const float*)d_in[2];  // [1024,1024]
  float* out = (float*)d_out;                  // [2,2048,1024]

  char* ws = (char*)d_ws;
  size_t off = 0;
  auto alloc = [&](size_t bytes) {
    char* p = ws + off;
    off += (bytes + 255) & ~(size_t)255;
    return p;
  };
  const size_t MT = (size_t)BSZ * TSEQ;  // 4096
  u16* xb    = (u16*)alloc(MT * DMODEL * 2);          // x bf16
  u16* wqkvT = (u16*)alloc((size_t)3 * DMODEL * DMODEL * 2);  // [3072][1024]
  u16* woutT = (u16*)alloc((size_t)DMODEL * DMODEL * 2);      // [1024][1024]
  u16* qkv   = (u16*)alloc(MT * 3 * DMODEL * 2);      // [4096][3072]
  u16* Qh    = (u16*)alloc(MT * DMODEL * 2);          // [B*H][T][DH]
  u16* Kh    = (u16*)alloc(MT * DMODEL * 2);
  u16* Vh    = (u16*)alloc(MT * DMODEL * 2);
  u16* aout  = (u16*)alloc(MT * DMODEL * 2);          // attn out [B,T,D] bf16
  float* cosT = (float*)alloc((size_t)TSEQ * 32 * 4);
  float* sinT = (float*)alloc((size_t)TSEQ * 32 * 4);
  if (ws_size < off) return;  // workspace too small: fail loudly via absmax

  k_cvt<<<(MT * DMODEL / 4 + 255) / 256, 256, 0, stream>>>(x, xb, MT * DMODEL / 4);
  k_transpose_cvt<<<dim3(48, 16), 256, 0, stream>>>(w_qkv, wqkvT, DMODEL, 3 * DMODEL);
  k_transpose_cvt<<<dim3(16, 16), 256, 0, stream>>>(w_out, woutT, DMODEL, DMODEL);
  k_rope_table<<<(TSEQ * 32) / 256, 256, 0, stream>>>(cosT, sinT);
  k_gemm<u16><<<dim3(24, 32), 256, 0, stream>>>(xb, wqkvT, qkv, (int)MT, 3 * DMODEL, DMODEL);
  k_rope_apply<<<(int)(MT * DMODEL / 256), 256, 0, stream>>>(qkv, cosT, sinT, Qh, Kh, Vh);
  k_flash<<<dim3(TSEQ / 64, BSZ * NHEAD), 256, 0, stream>>>(Qh, Kh, Vh, aout);
  k_gemm<float><<<dim3(8, 32), 256, 0, stream>>>(aout, woutT, out, (int)MT, DMODEL, DMODEL);
}

// Round 4
// 293.562 us; speedup vs baseline: 1.0751x; 1.0751x over previous
//
#include <hip/hip_runtime.h>

typedef __bf16 bf16x8 __attribute__((ext_vector_type(8)));
typedef float f32x4 __attribute__((ext_vector_type(4)));
typedef unsigned int u32x4 __attribute__((ext_vector_type(4)));
typedef unsigned int u32x2 __attribute__((ext_vector_type(2)));
typedef unsigned short u16;
typedef unsigned int u32;

// ---- constants for this problem ----
#define BSZ 2
#define TSEQ 2048
#define DMODEL 1024
#define NHEAD 16
#define DHEAD 64

// async global->LDS, 16B per lane, dest = wave-uniform base + lane*16
#define GLDS(gp, lp)                                                        \
  __builtin_amdgcn_global_load_lds(                                         \
      (const __attribute__((address_space(1))) void*)(gp),                  \
      (__attribute__((address_space(3))) void*)(lp), 16, 0, 0)

__device__ __forceinline__ u16 f2bf(float f) {
  u32 u = __builtin_bit_cast(u32, f);
  u32 r = (u + 0x7fffu + ((u >> 16) & 1u)) >> 16;   // RNE
  return (u16)r;
}
__device__ __forceinline__ float bf2f(u16 h) {
  return __builtin_bit_cast(float, (u32)h << 16);
}

// ---------------- fp32 -> bf16 convert (4 elems/thread) ----------------
__global__ void k_cvt(const float* __restrict__ in, u16* __restrict__ out, int n4) {
  int i = blockIdx.x * 256 + threadIdx.x;
  if (i >= n4) return;
  float4 v = ((const float4*)in)[i];
  ushort4 o;
  o.x = f2bf(v.x); o.y = f2bf(v.y); o.z = f2bf(v.z); o.w = f2bf(v.w);
  ((ushort4*)out)[i] = o;
}

// ------------- transpose + convert: in [K][N] f32 -> out [N][K] bf16 -------------
__global__ void k_transpose_cvt(const float* __restrict__ in, u16* __restrict__ out,
                                int K, int N) {
  __shared__ float tile[64][65];
  int n0 = blockIdx.x * 64, k0 = blockIdx.y * 64;
  int tx = threadIdx.x & 63, ty = threadIdx.x >> 6;
#pragma unroll
  for (int i = ty; i < 64; i += 4)
    tile[i][tx] = in[(size_t)(k0 + i) * N + n0 + tx];
  __syncthreads();
#pragma unroll
  for (int i = ty; i < 64; i += 4)
    out[(size_t)(n0 + i) * K + k0 + tx] = f2bf(tile[tx][i]);
}

// ---------------- RoPE cos/sin table: [T][32] each ----------------
__global__ void k_rope_table(float* __restrict__ cosT, float* __restrict__ sinT) {
  int idx = blockIdx.x * 256 + threadIdx.x;  // T*32
  int t = idx >> 5, f = idx & 31;
  float inv_freq = powf(10000.0f, -(float)(2 * f) / 64.0f);
  float ang = (float)t * inv_freq;
  float s, c;
  sincosf(ang, &s, &c);
  cosT[idx] = c;
  sinT[idx] = s;
}

// ---------------- GEMM: C[M][N] = A[M][K] * Bt[N][K]^T (m97-style staging) ----------------
__device__ __forceinline__ void store_out(u16* C, size_t i, float v) { C[i] = f2bf(v); }
__device__ __forceinline__ void store_out(float* C, size_t i, float v) { C[i] = v; }

template <typename OutT>
__global__ __launch_bounds__(256) void k_gemm(const u16* __restrict__ A,
                                              const u16* __restrict__ Bt,
                                              OutT* __restrict__ C, int M, int N, int K) {
  __shared__ __align__(16) u16 a_lds[128][32];   // unpadded: required by global_load_lds
  __shared__ __align__(16) u16 b_lds[128][32];
  int m0 = blockIdx.y * 128, n0 = blockIdx.x * 128;
  int tid = threadIdx.x;
  int w = tid >> 6, l = tid & 63, lr = l & 15, lg = l >> 4;
  int wr = (w >> 1) * 64, wc = (w & 1) * 64;
  int grow = l >> 2;        // 0..15 row within 16-row chunk
  int gcol = (l & 3) * 8;   // k-chunk (8 bf16 = 16B)
  f32x4 acc[4][4] = {};

  // each wave stages chunks w and w+4 (16 rows each) of both A and B tiles
  const u16* a0 = A + (size_t)(m0 + w * 16 + grow) * K + gcol;
  const u16* a1 = A + (size_t)(m0 + (w + 4) * 16 + grow) * K + gcol;
  const u16* b0 = Bt + (size_t)(n0 + w * 16 + grow) * K + gcol;
  const u16* b1 = Bt + (size_t)(n0 + (w + 4) * 16 + grow) * K + gcol;
  u16* la0 = &a_lds[w * 16][0];          // wave-uniform LDS bases
  u16* la1 = &a_lds[(w + 4) * 16][0];
  u16* lb0 = &b_lds[w * 16][0];
  u16* lb1 = &b_lds[(w + 4) * 16][0];

  for (int k0 = 0; k0 < K; k0 += 32) {
    GLDS(a0 + k0, la0);
    GLDS(a1 + k0, la1);
    GLDS(b0 + k0, lb0);
    GLDS(b1 + k0, lb1);
    __syncthreads();   // compiler drains vmcnt before barrier
    bf16x8 af[4], bfv[4];
#pragma unroll
    for (int mt = 0; mt < 4; ++mt)
      af[mt] = __builtin_bit_cast(bf16x8, *(const u32x4*)&a_lds[wr + mt * 16 + lr][lg * 8]);
#pragma unroll
    for (int nt = 0; nt < 4; ++nt)
      bfv[nt] = __builtin_bit_cast(bf16x8, *(const u32x4*)&b_lds[wc + nt * 16 + lr][lg * 8]);
    __builtin_amdgcn_s_setprio(1);
#pragma unroll
    for (int mt = 0; mt < 4; ++mt)
#pragma unroll
      for (int nt = 0; nt < 4; ++nt)
        acc[mt][nt] = __builtin_amdgcn_mfma_f32_16x16x32_bf16(af[mt], bfv[nt], acc[mt][nt], 0, 0, 0);
    __builtin_amdgcn_s_setprio(0);
    __syncthreads();   // all waves done reading before next stage
  }

#pragma unroll
  for (int mt = 0; mt < 4; ++mt)
#pragma unroll
    for (int nt = 0; nt < 4; ++nt)
#pragma unroll
      for (int r = 0; r < 4; ++r) {
        int row = m0 + wr + mt * 16 + lg * 4 + r;
        int col = n0 + wc + nt * 16 + lr;
        store_out(C, (size_t)row * N + col, acc[mt][nt][r]);
      }
}

// ---------------- RoPE apply + [B,T,3D] -> [B,H,T,DH] split ----------------
__global__ void k_rope_apply(const u16* __restrict__ qkv, const float* __restrict__ cosT,
                             const float* __restrict__ sinT, u16* __restrict__ Q,
                             u16* __restrict__ K, u16* __restrict__ V) {
  int idx = blockIdx.x * 256 + threadIdx.x;
  int d = idx & 63;
  int t = (idx >> 6) & 2047;
  int h = (idx >> 17) & 15;
  int b = idx >> 21;
  size_t row = (size_t)(b * TSEQ + t) * (3 * DMODEL);
  int cq = h * 64 + d;
  int cp = h * 64 + (d ^ 32);
  float q  = bf2f(qkv[row + cq]);
  float qp = bf2f(qkv[row + cp]);
  float k  = bf2f(qkv[row + DMODEL + cq]);
  float kp = bf2f(qkv[row + DMODEL + cp]);
  float v  = bf2f(qkv[row + 2 * DMODEL + cq]);
  int f = d & 31;
  float c = cosT[t * 32 + f], s = sinT[t * 32 + f];
  float sgn = (d < 32) ? -1.0f : 1.0f;
  float qr = (q * c + sgn * qp * s) * 0.125f;  // fold score scale into Q
  float kr = k * c + sgn * kp * s;
  Q[idx] = f2bf(qr);
  K[idx] = f2bf(kr);
  V[idx] = f2bf(v);
}

// ---------------- flash attention (causal), QBLK=64, KVBLK=64, 4 waves ----------------
// V staged in subtiled layout [S=s>>2][D=d>>4][s&3][d&15] and consumed via
// ds_read_b64_tr_b16 (hardware transpose read, m156/m162 mapping).
__global__ __launch_bounds__(256) void k_flash(const u16* __restrict__ Qg, const u16* __restrict__ Kg,
                                               const u16* __restrict__ Vg, u16* __restrict__ O) {
  __shared__ __align__(16) u16 k_lds[64][72];
  __shared__ __align__(16) u16 vsub[4096];       // 64x64 V tile, subtiled
  __shared__ __align__(16) u16 p_lds[4][16][72];
  int qb = gridDim.x - 1 - blockIdx.x;  // heavy blocks first
  int bh = blockIdx.y;                  // b*16+h
  int b = bh >> 4, h = bh & 15;
  size_t hoff = (size_t)bh * TSEQ * DHEAD;
  int tid = threadIdx.x, w = tid >> 6, l = tid & 63, lr = l & 15, lg = l >> 4;

  // Q fragments (registers, whole block)
  int qrow = qb * 64 + w * 16 + lr;
  const u16* qp = Qg + hoff + (size_t)qrow * 64 + lg * 8;
  bf16x8 qf0 = __builtin_bit_cast(bf16x8, *(const u32x4*)qp);
  bf16x8 qf1 = __builtin_bit_cast(bf16x8, *(const u32x4*)(qp + 32));

  f32x4 acc[4] = {};
  float mrow[4] = {-1e30f, -1e30f, -1e30f, -1e30f};
  float lrow[4] = {0.f, 0.f, 0.f, 0.f};

  int srow = tid >> 3;        // 0..31
  int g8 = tid & 7;
  int sc8 = g8 * 8;
  // tr-read per-lane base (bytes within LDS): region(S=2lg+h, D=n) + lr*8
  u32 vtr = (u32)(uintptr_t)vsub + (u32)(lg * 1024 + lr * 8);

  const u16* kbase = Kg + hoff;
  const u16* vbase = Vg + hoff;
  u32x4 kreg[2], vreg[2];
#pragma unroll
  for (int p = 0; p < 2; ++p) {   // prologue: tile kv=0 into regs
    int r = srow + p * 32;
    kreg[p] = *(const u32x4*)(kbase + (size_t)r * 64 + sc8);
    vreg[p] = *(const u32x4*)(vbase + (size_t)r * 64 + sc8);
  }

  for (int kv = 0; kv <= qb; ++kv) {
    __syncthreads();   // previous tile fully consumed
#pragma unroll
    for (int p = 0; p < 2; ++p) {
      int r = srow + p * 32;
      *(u32x4*)&k_lds[r][sc8] = kreg[p];
      // subtiled V write: contiguous 8 elems -> single b128, conflict-free
      int vo = ((r >> 2) * 4 + (g8 >> 1)) * 64 + (r & 3) * 16 + (g8 & 1) * 8;
      *(u32x4*)&vsub[vo] = vreg[p];
    }
    __syncthreads();
    if (kv < qb) {   // T14: prefetch next tile; latency hides under compute
#pragma unroll
      for (int p = 0; p < 2; ++p) {
        int r = (kv + 1) * 64 + srow + p * 32;
        kreg[p] = *(const u32x4*)(kbase + (size_t)r * 64 + sc8);
        vreg[p] = *(const u32x4*)(vbase + (size_t)r * 64 + sc8);
      }
    }

    // S = (Q*scale) K^T  -- 16x64 per wave
    f32x4 s[4];
    __builtin_amdgcn_s_setprio(1);
#pragma unroll
    for (int c = 0; c < 4; ++c) {
      const u16* kp2 = &k_lds[c * 16 + lr][lg * 8];
      bf16x8 kf0 = __builtin_bit_cast(bf16x8, *(const u32x4*)kp2);
      bf16x8 kf1 = __builtin_bit_cast(bf16x8, *(const u32x4*)(kp2 + 32));
      f32x4 z = {};
      z = __builtin_amdgcn_mfma_f32_16x16x32_bf16(qf0, kf0, z, 0, 0, 0);
      s[c] = __builtin_amdgcn_mfma_f32_16x16x32_bf16(qf1, kf1, z, 0, 0, 0);
    }
    __builtin_amdgcn_s_setprio(0);
    if (kv == qb) {  // diagonal block: causal mask (col > row)
#pragma unroll
      for (int c = 0; c < 4; ++c)
#pragma unroll
        for (int r = 0; r < 4; ++r)
          if (c * 16 + lr > w * 16 + lg * 4 + r) s[c][r] = -1e30f;
    }

    // online softmax (rows spread across 16-lane groups, 4 rows/lane)
    float rmax[4], rsum[4], alpha[4];
#pragma unroll
    for (int r = 0; r < 4; ++r)
      rmax[r] = fmaxf(fmaxf(s[0][r], s[1][r]), fmaxf(s[2][r], s[3][r]));
#pragma unroll
    for (int mset = 1; mset <= 8; mset <<= 1)
#pragma unroll
      for (int r = 0; r < 4; ++r)
        rmax[r] = fmaxf(rmax[r], __shfl_xor(rmax[r], mset, 64));
#pragma unroll
    for (int r = 0; r < 4; ++r) {
      float mn = fmaxf(mrow[r], rmax[r]);
      alpha[r] = __expf(mrow[r] - mn);
      mrow[r] = mn;
      rsum[r] = 0.0f;
    }
#pragma unroll
    for (int c = 0; c < 4; ++c)
#pragma unroll
      for (int r = 0; r < 4; ++r) {
        float pe = __expf(s[c][r] - mrow[r]);
        s[c][r] = pe;
        rsum[r] += pe;
      }
#pragma unroll
    for (int mset = 1; mset <= 8; mset <<= 1)
#pragma unroll
      for (int r = 0; r < 4; ++r)
        rsum[r] += __shfl_xor(rsum[r], mset, 64);
#pragma unroll
    for (int r = 0; r < 4; ++r)
      lrow[r] = lrow[r] * alpha[r] + rsum[r];
#pragma unroll
    for (int n = 0; n < 4; ++n)
#pragma unroll
      for (int r = 0; r < 4; ++r)
        acc[n][r] *= alpha[r];

    // P (fp32, C-layout) -> bf16 via per-wave LDS round-trip
#pragma unroll
    for (int c = 0; c < 4; ++c)
#pragma unroll
      for (int r = 0; r < 4; ++r)
        p_lds[w][lg * 4 + r][c * 16 + lr] = f2bf(s[c][r]);
    bf16x8 pa0 = __builtin_bit_cast(bf16x8, *(const u32x4*)&p_lds[w][lr][lg * 8]);
    bf16x8 pa1 = __builtin_bit_cast(bf16x8, *(const u32x4*)&p_lds[w][lr][lg * 8 + 32]);

    // PV: B-fragments via hardware transpose reads, two n at a time
#pragma unroll
    for (int half = 0; half < 2; ++half) {
      u32x2 t[8];
#pragma unroll
      for (int n2 = 0; n2 < 2; ++n2) {
        int n = half * 2 + n2;
#pragma unroll
        for (int hh = 0; hh < 2; ++hh) {
          u32 alo = vtr + (u32)(hh * 512 + n * 128);
          u32 ahi = alo + 4096;
          asm volatile("ds_read_b64_tr_b16 %0, %1" : "=v"(t[n2 * 4 + hh]) : "v"(alo) : "memory");
          asm volatile("ds_read_b64_tr_b16 %0, %1" : "=v"(t[n2 * 4 + 2 + hh]) : "v"(ahi) : "memory");
        }
      }
      asm volatile("s_waitcnt lgkmcnt(0)" ::: "memory");
      __builtin_amdgcn_sched_barrier(0);
      __builtin_amdgcn_s_setprio(1);
#pragma unroll
      for (int n2 = 0; n2 < 2; ++n2) {
        int n = half * 2 + n2;
        u32x4 vlo, vhi;
        vlo[0] = t[n2 * 4 + 0][0]; vlo[1] = t[n2 * 4 + 0][1];
        vlo[2] = t[n2 * 4 + 1][0]; vlo[3] = t[n2 * 4 + 1][1];
        vhi[0] = t[n2 * 4 + 2][0]; vhi[1] = t[n2 * 4 + 2][1];
        vhi[2] = t[n2 * 4 + 3][0]; vhi[3] = t[n2 * 4 + 3][1];
        acc[n] = __builtin_amdgcn_mfma_f32_16x16x32_bf16(pa0, __builtin_bit_cast(bf16x8, vlo), acc[n], 0, 0, 0);
        acc[n] = __builtin_amdgcn_mfma_f32_16x16x32_bf16(pa1, __builtin_bit_cast(bf16x8, vhi), acc[n], 0, 0, 0);
      }
      __builtin_amdgcn_s_setprio(0);
    }
  }

  // epilogue: normalize, write [B,T,H*DH]
#pragma unroll
  for (int n = 0; n < 4; ++n)
#pragma unroll
    for (int r = 0; r < 4; ++r) {
      int t = qb * 64 + w * 16 + lg * 4 + r;
      int dd = n * 16 + lr;
      float ov = acc[n][r] / lrow[r];
      O[(size_t)(b * TSEQ + t) * DMODEL + h * 64 + dd] = f2bf(ov);
    }
}

extern "C" void kernel_launch(void* const* d_in, const int* in_sizes, int n_in,
                              void* d_out, int out_size, void* d_ws, size_t ws_size,
                              hipStream_t stream) {
  const float* x     = (const float*)d_in[0];  // [2,2048,1024]
  const float* w_qkv = (const float*)d_in[1];  // [1024,3072]
  const float* w_out = (const float*)d_in[2];  // [1024,1024]
  float* out = (float*)d_out;                  // [2,2048,1024]

  char* ws = (char*)d_ws;
  size_t off = 0;
  auto alloc = [&](size_t bytes) {
    char* p = ws + off;
    off += (bytes + 255) & ~(size_t)255;
    return p;
  };
  const size_t MT = (size_t)BSZ * TSEQ;  // 4096
  u16* xb    = (u16*)alloc(MT * DMODEL * 2);
  u16* wqkvT = (u16*)alloc((size_t)3 * DMODEL * DMODEL * 2);
  u16* woutT = (u16*)alloc((size_t)DMODEL * DMODEL * 2);
  u16* qkv   = (u16*)alloc(MT * 3 * DMODEL * 2);
  u16* Qh    = (u16*)alloc(MT * DMODEL * 2);
  u16* Kh    = (u16*)alloc(MT * DMODEL * 2);
  u16* Vh    = (u16*)alloc(MT * DMODEL * 2);
  u16* aout  = (u16*)alloc(MT * DMODEL * 2);
  float* cosT = (float*)alloc((size_t)TSEQ * 32 * 4);
  float* sinT = (float*)alloc((size_t)TSEQ * 32 * 4);
  if (ws_size < off) return;

  k_cvt<<<(MT * DMODEL / 4 + 255) / 256, 256, 0, stream>>>(x, xb, MT * DMODEL / 4);
  k_transpose_cvt<<<dim3(48, 16), 256, 0, stream>>>(w_qkv, wqkvT, DMODEL, 3 * DMODEL);
  k_transpose_cvt<<<dim3(16, 16), 256, 0, stream>>>(w_out, woutT, DMODEL, DMODEL);
  k_rope_table<<<(TSEQ * 32) / 256, 256, 0, stream>>>(cosT, sinT);
  k_gemm<u16><<<dim3(24, 32), 256, 0, stream>>>(xb, wqkvT, qkv, (int)MT, 3 * DMODEL, DMODEL);
  k_rope_apply<<<(int)(MT * DMODEL / 256), 256, 0, stream>>>(qkv, cosT, sinT, Qh, Kh, Vh);
  k_flash<<<dim3(TSEQ / 64, BSZ * NHEAD), 256, 0, stream>>>(Qh, Kh, Vh, aout);
  k_gemm<float><<<dim3(8, 32), 256, 0, stream>>>(aout, woutT, out, (int)MT, DMODEL, DMODEL);
}